// Round 4
// baseline (2209.643 us; speedup 1.0000x reference)
//
#include <hip/hip_runtime.h>
#include <hip/hip_bf16.h>

#define NTOK 8192
#define HID 1024
#define NH 4
#define DK 256
#define DV 256
#define SEQ 4096
#define NCHUNK 128

// ---------------------------------------------------------------- GEMM f32
#define BM 128
#define BN 128
#define BKK 16
__global__ __launch_bounds__(256) void gemm_f32(const float* __restrict__ A,
    const float* __restrict__ B, float* __restrict__ C, int M, int N, int K) {
  __shared__ __align__(16) float As[BKK][BM + 4];
  __shared__ __align__(16) float Bs[BKK][BN + 4];
  int tid = threadIdx.x;
  int bm = blockIdx.y * BM, bn = blockIdx.x * BN;
  int tx = tid & 15, ty = tid >> 4;
  float acc[8][8];
  #pragma unroll
  for (int i = 0; i < 8; ++i)
    #pragma unroll
    for (int j = 0; j < 8; ++j) acc[i][j] = 0.f;
  for (int k0 = 0; k0 < K; k0 += BKK) {
    #pragma unroll
    for (int jj = 0; jj < 2; ++jj) {
      int v = tid + (jj << 8);
      int row = v >> 2, kk = (v & 3) << 2;
      float4 a = *(const float4*)&A[(size_t)(bm + row) * K + k0 + kk];
      As[kk + 0][row] = a.x; As[kk + 1][row] = a.y;
      As[kk + 2][row] = a.z; As[kk + 3][row] = a.w;
      int k2 = v >> 5, cl = (v & 31) << 2;
      *(float4*)&Bs[k2][cl] = *(const float4*)&B[(size_t)(k0 + k2) * N + bn + cl];
    }
    __syncthreads();
    #pragma unroll
    for (int k = 0; k < BKK; ++k) {
      float af[8], bf[8];
      *(float4*)&af[0] = *(const float4*)&As[k][ty * 8];
      *(float4*)&af[4] = *(const float4*)&As[k][ty * 8 + 4];
      *(float4*)&bf[0] = *(const float4*)&Bs[k][tx * 8];
      *(float4*)&bf[4] = *(const float4*)&Bs[k][tx * 8 + 4];
      #pragma unroll
      for (int i = 0; i < 8; ++i)
        #pragma unroll
        for (int j = 0; j < 8; ++j) acc[i][j] += af[i] * bf[j];
    }
    __syncthreads();
  }
  #pragma unroll
  for (int i = 0; i < 8; ++i) {
    size_t off = (size_t)(bm + ty * 8 + i) * N + bn + tx * 8;
    *(float4*)&C[off]     = make_float4(acc[i][0], acc[i][1], acc[i][2], acc[i][3]);
    *(float4*)&C[off + 4] = make_float4(acc[i][4], acc[i][5], acc[i][6], acc[i][7]);
  }
}

// ---------------------------------------------------------- causal conv K=4 + silu
__global__ __launch_bounds__(256) void conv_silu_k(const float* __restrict__ x,
    const float* __restrict__ w, float* __restrict__ y) {
  int idx = blockIdx.x * 256 + threadIdx.x;
  int ch = idx & (HID - 1);
  int n = idx >> 10;
  int l = n & (SEQ - 1);
  float4 wv = *(const float4*)&w[ch * 4];
  float s = wv.w * x[idx];
  if (l >= 1) s += wv.z * x[idx - HID];
  if (l >= 2) s += wv.y * x[idx - 2 * HID];
  if (l >= 3) s += wv.x * x[idx - 3 * HID];
  y[idx] = s / (1.f + expf(-s));   // silu
}

// ---------------------------------------------------------------- beta = sigmoid(hs@Wb)
__global__ __launch_bounds__(256) void beta_k(const float* __restrict__ hs,
    const float* __restrict__ Wb, float* __restrict__ beta) {
  int wv = threadIdx.x >> 6, lane = threadIdx.x & 63;
  int n = blockIdx.x * 4 + wv;
  const float* row = hs + (size_t)n * HID;
  float a0 = 0, a1 = 0, a2 = 0, a3 = 0;
  for (int k = lane; k < HID; k += 64) {
    float h = row[k];
    float4 wb = *(const float4*)&Wb[k * 4];
    a0 += h * wb.x; a1 += h * wb.y; a2 += h * wb.z; a3 += h * wb.w;
  }
  #pragma unroll
  for (int off = 32; off; off >>= 1) {
    a0 += __shfl_down(a0, off); a1 += __shfl_down(a1, off);
    a2 += __shfl_down(a2, off); a3 += __shfl_down(a3, off);
  }
  if (lane == 0) {
    float4 r = make_float4(1.f / (1.f + expf(-a0)), 1.f / (1.f + expf(-a1)),
                           1.f / (1.f + expf(-a2)), 1.f / (1.f + expf(-a3)));
    *(float4*)&beta[n * 4] = r;
  }
}

// --------------------------------------------- phase A (no spills)
__global__ __launch_bounds__(256) void phaseA_k(
    float* __restrict__ qg, float* __restrict__ kg, const float* __restrict__ vg,
    const float* __restrict__ betag, float* __restrict__ ug, float* __restrict__ wg,
    float* __restrict__ alg) {
  __shared__ __align__(16) float kn[32][260];
  __shared__ __align__(16) float qn[32][260];
  __shared__ __align__(16) float att[32][36];
  __shared__ float bet[32];
  int blk = blockIdx.x;
  int c = blk & (NCHUNK - 1);
  int bh = blk >> 7;
  int h = bh & 3, b = bh >> 2;
  int n0 = b * SEQ + c * 32;
  size_t rowbase = (size_t)n0 * HID + h * DK;
  int tid = threadIdx.x;
  int wv = tid >> 6, L = tid & 63;

  if (tid < 32) bet[tid] = betag[(n0 + tid) * NH + h];

  {  // stage + l2norm k
    float4 ka[8];
    #pragma unroll
    for (int j = 0; j < 8; ++j)
      ka[j] = *(const float4*)&kg[rowbase + (size_t)(wv + 4 * j) * HID + 4 * L];
    #pragma unroll
    for (int j = 0; j < 8; ++j) {
      float ss = ka[j].x * ka[j].x + ka[j].y * ka[j].y + ka[j].z * ka[j].z + ka[j].w * ka[j].w;
      #pragma unroll
      for (int m = 1; m < 64; m <<= 1) ss += __shfl_xor(ss, m);
      float sc = 1.f / sqrtf(ss + 1e-6f);
      int row = wv + 4 * j;
      float4 r = make_float4(ka[j].x * sc, ka[j].y * sc, ka[j].z * sc, ka[j].w * sc);
      *(float4*)&kn[row][4 * L] = r;
      *(float4*)&kg[rowbase + (size_t)row * HID + 4 * L] = r;
    }
  }
  {  // stage + l2norm q
    float4 qa[8];
    #pragma unroll
    for (int j = 0; j < 8; ++j)
      qa[j] = *(const float4*)&qg[rowbase + (size_t)(wv + 4 * j) * HID + 4 * L];
    #pragma unroll
    for (int j = 0; j < 8; ++j) {
      float ss = qa[j].x * qa[j].x + qa[j].y * qa[j].y + qa[j].z * qa[j].z + qa[j].w * qa[j].w;
      #pragma unroll
      for (int m = 1; m < 64; m <<= 1) ss += __shfl_xor(ss, m);
      float sc = 1.f / sqrtf(ss + 1e-6f);
      int row = wv + 4 * j;
      float4 r = make_float4(qa[j].x * sc, qa[j].y * sc, qa[j].z * sc, qa[j].w * sc);
      *(float4*)&qn[row][4 * L] = r;
      *(float4*)&qg[rowbase + (size_t)row * HID + 4 * L] = r;
    }
  }
  __syncthreads();

  {  // A = -(k*beta) @ kn^T strict-lower, 2x2 tile
    int i0 = (tid >> 4) << 1, j0 = (tid & 15) << 1;
    float a00 = 0, a01 = 0, a10 = 0, a11 = 0;
    #pragma unroll 4
    for (int e = 0; e < 256; e += 4) {
      float4 x0 = *(const float4*)&kn[i0][e];
      float4 x1 = *(const float4*)&kn[i0 + 1][e];
      float4 y0 = *(const float4*)&kn[j0][e];
      float4 y1 = *(const float4*)&kn[j0 + 1][e];
      a00 += x0.x * y0.x + x0.y * y0.y + x0.z * y0.z + x0.w * y0.w;
      a01 += x0.x * y1.x + x0.y * y1.y + x0.z * y1.z + x0.w * y1.w;
      a10 += x1.x * y0.x + x1.y * y0.y + x1.z * y0.z + x1.w * y0.w;
      a11 += x1.x * y1.x + x1.y * y1.y + x1.z * y1.z + x1.w * y1.w;
    }
    float bi0 = bet[i0], bi1 = bet[i0 + 1];
    att[i0][j0]         = (j0 < i0)         ? -bi0 * a00 : 0.f;
    att[i0][j0 + 1]     = (j0 + 1 < i0)     ? -bi0 * a01 : 0.f;
    att[i0 + 1][j0]     = (j0 < i0 + 1)     ? -bi1 * a10 : 0.f;
    att[i0 + 1][j0 + 1] = (j0 + 1 < i0 + 1) ? -bi1 * a11 : 0.f;
  }
  {  // attn_loc = (qn @ kn^T) * incl_low
    float* alp = alg + (size_t)(bh * NCHUNK + c) * 1024;
    int i0 = (tid >> 4) << 1, j0 = (tid & 15) << 1;
    float a00 = 0, a01 = 0, a10 = 0, a11 = 0;
    #pragma unroll 4
    for (int e = 0; e < 256; e += 4) {
      float4 x0 = *(const float4*)&qn[i0][e];
      float4 x1 = *(const float4*)&qn[i0 + 1][e];
      float4 y0 = *(const float4*)&kn[j0][e];
      float4 y1 = *(const float4*)&kn[j0 + 1][e];
      a00 += x0.x * y0.x + x0.y * y0.y + x0.z * y0.z + x0.w * y0.w;
      a01 += x0.x * y1.x + x0.y * y1.y + x0.z * y1.z + x0.w * y1.w;
      a10 += x1.x * y0.x + x1.y * y0.y + x1.z * y0.z + x1.w * y0.w;
      a11 += x1.x * y1.x + x1.y * y1.y + x1.z * y1.z + x1.w * y1.w;
    }
    alp[i0 * 32 + j0]           = (j0 <= i0)         ? a00 : 0.f;
    alp[i0 * 32 + j0 + 1]       = (j0 + 1 <= i0)     ? a01 : 0.f;
    alp[(i0 + 1) * 32 + j0]     = (j0 <= i0 + 1)     ? a10 : 0.f;
    alp[(i0 + 1) * 32 + j0 + 1] = (j0 + 1 <= i0 + 1) ? a11 : 0.f;
  }

  // prefetch v column into regs
  float vreg[32];
  {
    int d = tid;
    #pragma unroll
    for (int j = 0; j < 32; ++j)
      vreg[j] = vg[rowbase + (size_t)j * HID + d];
  }
  __syncthreads();

  // forward substitution in LDS (rolled, no register arrays)
  if (tid < 32) {
    int j = tid;
    for (int i = 1; i < 32; ++i) {
      float upd = 0.f;
      for (int k = j + 1; k < i; ++k)
        upd += att[i][k] * att[k][j];
      if (j < i) att[i][j] += upd;
    }
  }
  __syncthreads();

  {  // u = T@(v*beta), w = T@(k*beta); T = att + I
    int d = tid;
    #pragma unroll
    for (int j = 0; j < 32; ++j) vreg[j] *= bet[j];
    for (int i = 0; i < 32; ++i) {
      float s = vreg[i];
      #pragma unroll
      for (int j4 = 0; j4 < 32; j4 += 4) {
        float4 av = *(const float4*)&att[i][j4];
        s += av.x * vreg[j4] + av.y * vreg[j4 + 1] + av.z * vreg[j4 + 2] + av.w * vreg[j4 + 3];
      }
      ug[rowbase + (size_t)i * HID + d] = s;
    }
    float wreg[32];
    #pragma unroll
    for (int j = 0; j < 32; ++j) wreg[j] = kn[j][d] * bet[j];
    for (int i = 0; i < 32; ++i) {
      float s = wreg[i];
      #pragma unroll
      for (int j4 = 0; j4 < 32; j4 += 4) {
        float4 av = *(const float4*)&att[i][j4];
        s += av.x * wreg[j4] + av.y * wreg[j4 + 1] + av.z * wreg[j4 + 2] + av.w * wreg[j4 + 3];
      }
      wg[rowbase + (size_t)i * HID + d] = s;
    }
  }
}

// --------------------------------------------- phase B: sequential chunk scan
// Rewritten: single top-of-chunk latency point via global_load_lds prefetch
// (issued during previous chunk's output phase), XCD swizzle (same bh -> same
// XCD for L2 sharing), conflict-free red layout, 4 barriers/chunk.
__device__ __forceinline__ void stage_rows_lds(const float* gbase, float* lds0,
                                               int wv, int L) {
  #pragma unroll
  for (int j = 0; j < 8; ++j) {
    int row = wv * 8 + j;
    const float* src = gbase + (size_t)row * HID + L * 4;
    float* dst = lds0 + row * 260;
    __builtin_amdgcn_global_load_lds(
        (const __attribute__((address_space(1))) unsigned int*)src,
        (__attribute__((address_space(3))) unsigned int*)dst, 16, 0, 0);
  }
}

__global__ __launch_bounds__(256) void scan_k(
    const float* __restrict__ qn, const float* __restrict__ kn,
    const float* __restrict__ ug, const float* __restrict__ wg,
    const float* __restrict__ alg, float* __restrict__ og) {
  __shared__ __align__(16) float S[256][8];        // state slice
  __shared__ __align__(16) float stgw[32][260];
  __shared__ __align__(16) float stgq[32][260];
  __shared__ __align__(16) float stgk[32][260];
  __shared__ __align__(16) float albuf[32][33];
  __shared__ __align__(16) float uloc[32][12];
  __shared__ float red[8 * 296];                   // [dv][r][ks] flat, 2-way max

  int blk = blockIdx.x;
  int bh = blk & 7, dvg = blk >> 3;                // XCD swizzle: bh == XCD
  int h = bh & 3, b = bh >> 2;
  int d0 = dvg * 8;
  int tid = threadIdx.x;
  int wv = tid >> 6, L = tid & 63;
  int rP = tid >> 3, ks = tid & 7;                 // (row, kseg) for P1/P2
  int r2 = rP, dv2 = ks;                           // (row, dv) for R1/R2

  #pragma unroll
  for (int i = 0; i < 8; ++i) ((float*)S)[tid + (i << 8)] = 0.f;

  size_t bhbase = (size_t)b * SEQ * HID + h * DK;
  const float* alp0 = alg + (size_t)bh * NCHUNK * 1024;

  // prologue: stage chunk 0
  stage_rows_lds(wg + bhbase, &stgw[0][0], wv, L);
  stage_rows_lds(qn + bhbase, &stgq[0][0], wv, L);
  stage_rows_lds(kn + bhbase, &stgk[0][0], wv, L);
  float alr0 = alp0[tid], alr1 = alp0[tid + 256], alr2 = alp0[tid + 512], alr3 = alp0[tid + 768];
  float u_cur = ug[bhbase + (size_t)r2 * HID + d0 + dv2];

  for (int c = 0; c < NCHUNK; ++c) {
    size_t rowbase = bhbase + (size_t)c * 32 * HID;
    __syncthreads();   // bar_a: staged loads drained; prev S-commit visible
    {  // write albuf
      albuf[tid >> 5][tid & 31] = alr0;
      albuf[(tid + 256) >> 5][tid & 31] = alr1;
      albuf[(tid + 512) >> 5][tid & 31] = alr2;
      albuf[(tid + 768) >> 5][tid & 31] = alr3;
    }
    float a0=0,a1=0,a2=0,a3=0,a4=0,a5=0,a6=0,a7=0;
    #pragma unroll
    for (int t = 0; t < 32; ++t) {     // P1: w @ S partials
      int kk = (t << 3) + ks;
      float wvv = stgw[rP][kk];
      float4 s0 = *(const float4*)&S[kk][0];
      float4 s1 = *(const float4*)&S[kk][4];
      a0 += wvv*s0.x; a1 += wvv*s0.y; a2 += wvv*s0.z; a3 += wvv*s0.w;
      a4 += wvv*s1.x; a5 += wvv*s1.y; a6 += wvv*s1.z; a7 += wvv*s1.w;
    }
    {
      int base = rP * 9 + ks;
      red[0*296+base]=a0; red[1*296+base]=a1; red[2*296+base]=a2; red[3*296+base]=a3;
      red[4*296+base]=a4; red[5*296+base]=a5; red[6*296+base]=a6; red[7*296+base]=a7;
    }
    __syncthreads();   // bar_b
    {  // R1: uloc = u - w@S
      float s = 0.f;
      int base = dv2 * 296 + r2 * 9;
      #pragma unroll
      for (int k2 = 0; k2 < 8; ++k2) s += red[base + k2];
      uloc[r2][dv2] = u_cur - s;
    }
    __syncthreads();   // bar_c
    a0=0;a1=0;a2=0;a3=0;a4=0;a5=0;a6=0;a7=0;
    #pragma unroll
    for (int t = 0; t < 32; ++t) {     // P2: q @ S partials
      int kk = (t << 3) + ks;
      float qvv = stgq[rP][kk];
      float4 s0 = *(const float4*)&S[kk][0];
      float4 s1 = *(const float4*)&S[kk][4];
      a0 += qvv*s0.x; a1 += qvv*s0.y; a2 += qvv*s0.z; a3 += qvv*s0.w;
      a4 += qvv*s1.x; a5 += qvv*s1.y; a6 += qvv*s1.z; a7 += qvv*s1.w;
    }
    {
      int base = rP * 9 + ks;
      red[0*296+base]=a0; red[1*296+base]=a1; red[2*296+base]=a2; red[3*296+base]=a3;
      red[4*296+base]=a4; red[5*296+base]=a5; red[6*296+base]=a6; red[7*296+base]=a7;
    }
    float d0r=0,d1r=0,d2r=0,d3r=0,d4r=0,d5r=0,d6r=0,d7r=0;
    #pragma unroll
    for (int rr = 0; rr < 32; ++rr) {  // P4: S-delta = k^T @ uloc (thread owns S row tid)
      float kv = stgk[rr][tid];
      float4 u0 = *(const float4*)&uloc[rr][0];
      float4 u1 = *(const float4*)&uloc[rr][4];
      d0r += kv*u0.x; d1r += kv*u0.y; d2r += kv*u0.z; d3r += kv*u0.w;
      d4r += kv*u1.x; d5r += kv*u1.y; d6r += kv*u1.z; d7r += kv*u1.w;
    }
    __syncthreads();   // bar_d: red(P2) ready; all S reads complete
    if (c + 1 < NCHUNK) {   // issue next chunk's staging (drained at next bar_a)
      size_t rbn = rowbase + (size_t)32 * HID;
      stage_rows_lds(wg + rbn, &stgw[0][0], wv, L);
      stage_rows_lds(qn + rbn, &stgq[0][0], wv, L);
      stage_rows_lds(kn + rbn, &stgk[0][0], wv, L);
      const float* alp = alp0 + (size_t)(c + 1) * 1024;
      alr0 = alp[tid]; alr1 = alp[tid + 256]; alr2 = alp[tid + 512]; alr3 = alp[tid + 768];
      u_cur = ug[rbn + (size_t)r2 * HID + d0 + dv2];
    }
    {  // R2: o = q@S + al@uloc
      float s = 0.f;
      int base = dv2 * 296 + r2 * 9;
      #pragma unroll
      for (int k2 = 0; k2 < 8; ++k2) s += red[base + k2];
      #pragma unroll
      for (int j2 = 0; j2 < 32; ++j2) s += albuf[r2][j2] * uloc[j2][dv2];
      og[rowbase + (size_t)r2 * HID + d0 + dv2] = s;
    }
    {  // commit S
      float4 c0 = *(const float4*)&S[tid][0];
      float4 c1 = *(const float4*)&S[tid][4];
      c0.x += d0r; c0.y += d1r; c0.z += d2r; c0.w += d3r;
      c1.x += d4r; c1.y += d5r; c1.z += d6r; c1.w += d7r;
      *(float4*)&S[tid][0] = c0;
      *(float4*)&S[tid][4] = c1;
    }
  }
}

// -------------------------------------- fused depthwise FIR (K=64 long + K=5 short)
#define VS 196
__global__ __launch_bounds__(256) void fir_fused_k(const float* __restrict__ v,
    const float* __restrict__ wl, const float* __restrict__ wsrt,
    float* __restrict__ yl, float* __restrict__ ys) {
  __shared__ __align__(16) float vt[64 * VS];
  __shared__ __align__(16) float wlds[64 * 68];
  __shared__ float wslds[64 * 9];
  int blk = blockIdx.x;
  int ch0 = (blk & 15) << 6;
  int tok0 = (blk >> 4) << 7;
  int tid = threadIdx.x;
  {
    const float4* src = (const float4*)(wl + (size_t)ch0 * 64);
    #pragma unroll
    for (int i = 0; i < 4; ++i) {
      int f = tid + (i << 8);
      int c = f >> 4, g = f & 15;
      float4 x = src[f];
      *(float4*)&wlds[c * 68 + (g << 2)] = x;
    }
  }
  if (tid < 64) {
    #pragma unroll
    for (int j = 0; j < 5; ++j)
      wslds[tid * 9 + j] = wsrt[(size_t)(ch0 + tid) * 5 + j];
  }
  {
    int chg = tid & 15, rt = tid >> 4;
    int lb = tok0 & (SEQ - 1);
    #pragma unroll
    for (int m = 0; m < 12; ++m) {
      int rr = rt + (m << 4);
      if (rr < 191) {
        float4 x = make_float4(0.f, 0.f, 0.f, 0.f);
        if (lb + rr - 63 >= 0)
          x = *(const float4*)&v[(size_t)(tok0 - 63 + rr) * HID + ch0 + (chg << 2)];
        int cb = chg << 2;
        vt[(cb + 0) * VS + rr] = x.x;
        vt[(cb + 1) * VS + rr] = x.y;
        vt[(cb + 2) * VS + rr] = x.z;
        vt[(cb + 3) * VS + rr] = x.w;
      }
    }
  }
  __syncthreads();
  int ch = tid & 63, pt = tid >> 6;
  int p0 = pt << 5;
  const float* vrow = &vt[ch * VS + p0];
  float acc[32];
  #pragma unroll
  for (int p = 0; p < 32; ++p) acc[p] = 0.f;
  for (int g = 0; g < 16; ++g) {
    float win[36];
    #pragma unroll
    for (int j = 0; j < 9; ++j) {
      float4 x = *(const float4*)&vrow[(g << 2) + (j << 2)];
      win[4 * j] = x.x; win[4 * j + 1] = x.y; win[4 * j + 2] = x.z; win[4 * j + 3] = x.w;
    }
    float4 wq = *(const float4*)&wlds[ch * 68 + (g << 2)];
    #pragma unroll
    for (int p = 0; p < 32; ++p)
      acc[p] += wq.x * win[p] + wq.y * win[p + 1] + wq.z * win[p + 2] + wq.w * win[p + 3];
  }
  #pragma unroll
  for (int p = 0; p < 32; ++p)
    yl[(size_t)(tok0 + p0 + p) * HID + ch0 + ch] = acc[p];
  float ws5[5];
  #pragma unroll
  for (int j = 0; j < 5; ++j) ws5[j] = wslds[ch * 9 + j];
  float swin[40];
  #pragma unroll
  for (int j = 0; j < 10; ++j) {
    float4 x = *(const float4*)&vrow[56 + (j << 2)];
    swin[4 * j] = x.x; swin[4 * j + 1] = x.y; swin[4 * j + 2] = x.z; swin[4 * j + 3] = x.w;
  }
  #pragma unroll
  for (int p = 0; p < 32; ++p) {
    float s = ws5[0] * swin[p + 3] + ws5[1] * swin[p + 4] + ws5[2] * swin[p + 5]
            + ws5[3] * swin[p + 6] + ws5[4] * swin[p + 7];
    ys[(size_t)(tok0 + p0 + p) * HID + ch0 + ch] = s;
  }
}

// ---------------------------------------------------------------- stats
__global__ __launch_bounds__(256) void stats_k(const float* __restrict__ ls,
    const float* __restrict__ ll, const float* __restrict__ dd,
    const float* __restrict__ vv, float* __restrict__ st) {
  int n = blockIdx.x;
  int h = threadIdx.x >> 6, lane = threadIdx.x & 63;
  size_t base = (size_t)n * HID + h * DV;
  const float* ptr[4] = {ls, ll, dd, vv};
  #pragma unroll
  for (int t = 0; t < 4; ++t) {
    const float* p = ptr[t] + base;
    float s1 = 0, s2 = 0, sa = 0;
    #pragma unroll
    for (int e = 0; e < 4; ++e) {
      float x = p[lane + e * 64];
      s1 += x; s2 += x * x; sa += fabsf(x);
    }
    #pragma unroll
    for (int off = 32; off; off >>= 1) {
      s1 += __shfl_down(s1, off); s2 += __shfl_down(s2, off); sa += __shfl_down(sa, off);
    }
    if (lane == 0) {
      float mean = s1 * (1.f / 256.f);
      float var = s2 * (1.f / 256.f) - mean * mean;
      float4 r = make_float4(mean, var, sa * (1.f / 256.f), sqrtf(s2));
      *(float4*)&st[(size_t)(n * NH + h) * 16 + t * 4] = r;
    }
  }
}

// --------------------------------------- gate MLP tail + softmax + fuse + RMSNorm
__global__ __launch_bounds__(256) void gate_fuse_k(
    const float* __restrict__ base, const float* __restrict__ st,
    const float* __restrict__ w1b, const float* __restrict__ b1,
    const float* __restrict__ w2, const float* __restrict__ b2,
    const float* __restrict__ ltemp,
    const float* __restrict__ ls, const float* __restrict__ ll,
    const float* __restrict__ dd, const float* __restrict__ vv,
    const float* __restrict__ onw, float* __restrict__ fused) {
  int n = blockIdx.x, tid = threadIdx.x;
  __shared__ float sst[4][16];
  __shared__ float wred[4][16];
  __shared__ float probs[4][4];
  __shared__ float o2red[4][4];
  __shared__ float rmss[4];
  if (tid < 64) sst[tid >> 4][tid & 15] = st[(size_t)n * 64 + tid];
  __syncthreads();
  float acc[4][4];
  #pragma unroll
  for (int a = 0; a < 4; ++a)
    #pragma unroll
    for (int cc = 0; cc < 4; ++cc) acc[a][cc] = 0.f;
  #pragma unroll
  for (int jj = 0; jj < 4; ++jj) {
    int j = tid + (jj << 8);
    float xb = base[(size_t)n * HID + j] + b1[j];
    float wr[16];
    #pragma unroll
    for (int s = 0; s < 16; ++s) wr[s] = w1b[s * 1024 + j];
    float4 w2j = *(const float4*)&w2[j * 4];
    #pragma unroll
    for (int hh = 0; hh < 4; ++hh) {
      float x = xb;
      #pragma unroll
      for (int s = 0; s < 16; ++s) x += sst[hh][s] * wr[s];
      float g = 0.5f * x * (1.f + erff(x * 0.70710678118654752f));
      acc[hh][0] += g * w2j.x; acc[hh][1] += g * w2j.y;
      acc[hh][2] += g * w2j.z; acc[hh][3] += g * w2j.w;
    }
  }
  #pragma unroll
  for (int hh = 0; hh < 4; ++hh)
    #pragma unroll
    for (int cc = 0; cc < 4; ++cc) {
      float v = acc[hh][cc];
      #pragma unroll
      for (int off = 32; off; off >>= 1) v += __shfl_down(v, off);
      if ((tid & 63) == 0) wred[tid >> 6][hh * 4 + cc] = v;
    }
  __syncthreads();
  if (tid < 4) {
    int hh = tid;
    float t = expf(ltemp[hh]);
    float lg[4], mx = -1e30f;
    #pragma unroll
    for (int cc = 0; cc < 4; ++cc) {
      float sv = wred[0][hh * 4 + cc] + wred[1][hh * 4 + cc] + wred[2][hh * 4 + cc]
               + wred[3][hh * 4 + cc] + b2[cc];
      lg[cc] = sv / t;
      mx = fmaxf(mx, lg[cc]);
    }
    float se = 0.f;
    #pragma unroll
    for (int cc = 0; cc < 4; ++cc) { lg[cc] = expf(lg[cc] - mx); se += lg[cc]; }
    float inv = 1.f / se;
    #pragma unroll
    for (int cc = 0; cc < 4; ++cc) probs[hh][cc] = 0.05f + 0.8f * lg[cc] * inv;
  }
  __syncthreads();
  int d = tid;
  float ov[4];
  #pragma unroll
  for (int hh = 0; hh < 4; ++hh) {
    size_t ix = (size_t)n * HID + hh * DV + d;
    float o = probs[hh][0] * ls[ix] + probs[hh][1] * ll[ix]
            + probs[hh][2] * dd[ix] + probs[hh][3] * vv[ix];
    ov[hh] = o;
    float v2 = o * o;
    #pragma unroll
    for (int off = 32; off; off >>= 1) v2 += __shfl_down(v2, off);
    if ((tid & 63) == 0) o2red[tid >> 6][hh] = v2;
  }
  __syncthreads();
  if (tid < 4) {
    float s = o2red[0][tid] + o2red[1][tid] + o2red[2][tid] + o2red[3][tid];
    rmss[tid] = 1.f / sqrtf(s * (1.f / 256.f) + 1e-5f);
  }
  __syncthreads();
  float wn = onw[d];
  #pragma unroll
  for (int hh = 0; hh < 4; ++hh)
    fused[(size_t)n * HID + hh * DV + d] = ov[hh] * rmss[hh] * wn;
}

// ---------------------------------------------------------------- launch
extern "C" void kernel_launch(void* const* d_in, const int* in_sizes, int n_in,
                              void* d_out, int out_size, void* d_ws, size_t ws_size,
                              hipStream_t stream) {
  (void)in_sizes; (void)n_in; (void)out_size; (void)ws_size;
  const float* hs  = (const float*)d_in[0];
  const float* Wq  = (const float*)d_in[1];
  const float* Wk  = (const float*)d_in[2];
  const float* Wv  = (const float*)d_in[3];
  const float* Wb  = (const float*)d_in[4];
  const float* cqw = (const float*)d_in[5];
  const float* ckw = (const float*)d_in[6];
  const float* cvw = (const float*)d_in[7];
  const float* fsw = (const float*)d_in[8];
  const float* flw = (const float*)d_in[9];
  const float* w1  = (const float*)d_in[10];
  const float* b1  = (const float*)d_in[11];
  const float* w2  = (const float*)d_in[12];
  const float* b2  = (const float*)d_in[13];
  const float* lt  = (const float*)d_in[14];
  const float* onw = (const float*)d_in[15];
  const float* Wo  = (const float*)d_in[16];
  float* out = (float*)d_out;
  float* ws = (float*)d_ws;
  const size_t BIG = (size_t)NTOK * HID;
  float* lin = ws;
  float* qb  = ws + BIG;      // q -> qn -> local_short
  float* kb  = ws + 2 * BIG;  // k -> kn -> local_long
  float* vb  = ws + 3 * BIG;  // v_direct
  float* ub  = ws + 4 * BIG;  // u -> fused
  float* wb  = ws + 5 * BIG;  // w -> MLP base
  float* db  = ws + 6 * BIG;  // delta_out
  float* betab  = ws + 7 * BIG;
  float* statsb = betab + (size_t)NTOK * NH;
  float* alocb  = statsb + (size_t)NTOK * NH * 16;

  dim3 gg(HID / BN, NTOK / BM);
  gemm_f32<<<gg, 256, 0, stream>>>(hs, Wq, lin, NTOK, HID, HID);
  conv_silu_k<<<NTOK * HID / 256, 256, 0, stream>>>(lin, cqw, qb);
  gemm_f32<<<gg, 256, 0, stream>>>(hs, Wk, lin, NTOK, HID, HID);
  conv_silu_k<<<NTOK * HID / 256, 256, 0, stream>>>(lin, ckw, kb);
  gemm_f32<<<gg, 256, 0, stream>>>(hs, Wv, lin, NTOK, HID, HID);
  conv_silu_k<<<NTOK * HID / 256, 256, 0, stream>>>(lin, cvw, vb);
  beta_k<<<NTOK / 4, 256, 0, stream>>>(hs, Wb, betab);
  phaseA_k<<<2 * NH * NCHUNK, 256, 0, stream>>>(qb, kb, vb, betab, ub, wb, alocb);
  scan_k<<<256, 256, 0, stream>>>(qb, kb, ub, wb, alocb, db);
  fir_fused_k<<<(NTOK / 128) * (HID / 64), 256, 0, stream>>>(vb, flw, fsw, kb, qb);
  stats_k<<<NTOK, 256, 0, stream>>>(qb, kb, db, vb, statsb);
  gemm_f32<<<gg, 256, 0, stream>>>(hs, w1, wb, NTOK, HID, HID);
  gate_fuse_k<<<NTOK, 256, 0, stream>>>(wb, statsb, w1 + 1024 * 1024, b1, w2, b2, lt,
                                        qb, kb, db, vb, onw, ub);
  gemm_f32<<<gg, 256, 0, stream>>>(ub, Wo, out, NTOK, HID, HID);
}

// Round 5
// 1861.736 us; speedup vs baseline: 1.1869x; 1.1869x over previous
//
#include <hip/hip_runtime.h>
#include <hip/hip_bf16.h>

#define NTOK 8192
#define HID 1024
#define NH 4
#define DK 256
#define DV 256
#define SEQ 4096
#define NCHUNK 128

using bf16x8 = __attribute__((ext_vector_type(8))) __bf16;
using f32x4  = __attribute__((ext_vector_type(4))) float;

__device__ __forceinline__ ushort f2bf(float f) {
  unsigned u = __builtin_bit_cast(unsigned, f);
  u += 0x7fffu + ((u >> 16) & 1u);          // round-to-nearest-even
  return (ushort)(u >> 16);
}

// ---------------------------------------------------------------- GEMM bf16 MFMA
// C[M,N] = A[M,K]@B[K,N] fp32 in/out, bf16 MFMA inside. 128x128 tile, BK=64.
// A LDS [m][k] stride 72, B LDS transposed [n][k] stride 72, XOR-8 k-swizzle.
#define GSTR 72
__global__ __launch_bounds__(256) void gemm_bf16(const float* __restrict__ A,
    const float* __restrict__ B, float* __restrict__ C, int M, int N, int K) {
  __shared__ __align__(16) ushort Asl[128 * GSTR];
  __shared__ __align__(16) ushort Bsl[128 * GSTR];
  int tid = threadIdx.x;
  int bm = blockIdx.y * 128, bn = blockIdx.x * 128;
  int w = tid >> 6, l = tid & 63;
  int wm = (w >> 1) * 64, wn = (w & 1) * 64;
  int lm = l & 15, lk8 = (l >> 4) * 8;
  f32x4 acc[4][4];
  #pragma unroll
  for (int i = 0; i < 4; ++i)
    #pragma unroll
    for (int j = 0; j < 4; ++j) acc[i][j] = (f32x4){0.f, 0.f, 0.f, 0.f};
  for (int k0 = 0; k0 < K; k0 += 64) {
    __syncthreads();
    #pragma unroll
    for (int j = 0; j < 8; ++j) {        // stage A (coalesced 256B reads)
      int idx = tid + (j << 8);
      int kq = idx & 15, m = idx >> 4;
      float4 a = *(const float4*)&A[(size_t)(bm + m) * K + k0 + kq * 4];
      ushort4 p; p.x = f2bf(a.x); p.y = f2bf(a.y); p.z = f2bf(a.z); p.w = f2bf(a.w);
      int off = m * GSTR + ((kq * 4) ^ (((m >> 3) & 1) << 3));
      *(ushort4*)&Asl[off] = p;
    }
    #pragma unroll
    for (int j = 0; j < 8; ++j) {        // stage B transposed (4 strided row reads)
      int idx = tid + (j << 8);
      int n = (idx & 15) + ((idx >> 8) << 4);
      int kq = (idx >> 4) & 15;
      const float* bp = &B[(size_t)(k0 + kq * 4) * N + bn + n];
      float b0 = bp[0], b1 = bp[N], b2 = bp[2 * N], b3 = bp[3 * N];
      ushort4 p; p.x = f2bf(b0); p.y = f2bf(b1); p.z = f2bf(b2); p.w = f2bf(b3);
      int off = n * GSTR + ((kq * 4) ^ (((n >> 3) & 1) << 3));
      *(ushort4*)&Bsl[off] = p;
    }
    __syncthreads();
    #pragma unroll
    for (int kk = 0; kk < 64; kk += 32) {
      bf16x8 af[4], bfr[4];
      #pragma unroll
      for (int mt = 0; mt < 4; ++mt) {
        int row = wm + mt * 16 + lm;
        int ko = (kk + lk8) ^ (((row >> 3) & 1) << 3);
        af[mt] = *(const bf16x8*)&Asl[row * GSTR + ko];
      }
      #pragma unroll
      for (int nt = 0; nt < 4; ++nt) {
        int row = wn + nt * 16 + lm;
        int ko = (kk + lk8) ^ (((row >> 3) & 1) << 3);
        bfr[nt] = *(const bf16x8*)&Bsl[row * GSTR + ko];
      }
      #pragma unroll
      for (int mt = 0; mt < 4; ++mt)
        #pragma unroll
        for (int nt = 0; nt < 4; ++nt)
          acc[mt][nt] = __builtin_amdgcn_mfma_f32_16x16x32_bf16(af[mt], bfr[nt],
                                                                acc[mt][nt], 0, 0, 0);
    }
  }
  int r4 = (l >> 4) * 4;
  #pragma unroll
  for (int mt = 0; mt < 4; ++mt)
    #pragma unroll
    for (int nt = 0; nt < 4; ++nt)
      #pragma unroll
      for (int r = 0; r < 4; ++r) {
        int row = bm + wm + mt * 16 + r4 + r;
        int col = bn + wn + nt * 16 + lm;
        C[(size_t)row * N + col] = acc[mt][nt][r];
      }
}

// ---------------------------------------------------------------- GEMM f32 (Wo only)
#define BM 128
#define BN 128
#define BKK 16
__global__ __launch_bounds__(256) void gemm_f32(const float* __restrict__ A,
    const float* __restrict__ B, float* __restrict__ C, int M, int N, int K) {
  __shared__ __align__(16) float As[BKK][BM + 4];
  __shared__ __align__(16) float Bs[BKK][BN + 4];
  int tid = threadIdx.x;
  int bm = blockIdx.y * BM, bn = blockIdx.x * BN;
  int tx = tid & 15, ty = tid >> 4;
  float acc[8][8];
  #pragma unroll
  for (int i = 0; i < 8; ++i)
    #pragma unroll
    for (int j = 0; j < 8; ++j) acc[i][j] = 0.f;
  for (int k0 = 0; k0 < K; k0 += BKK) {
    #pragma unroll
    for (int jj = 0; jj < 2; ++jj) {
      int v = tid + (jj << 8);
      int row = v >> 2, kk = (v & 3) << 2;
      float4 a = *(const float4*)&A[(size_t)(bm + row) * K + k0 + kk];
      As[kk + 0][row] = a.x; As[kk + 1][row] = a.y;
      As[kk + 2][row] = a.z; As[kk + 3][row] = a.w;
      int k2 = v >> 5, cl = (v & 31) << 2;
      *(float4*)&Bs[k2][cl] = *(const float4*)&B[(size_t)(k0 + k2) * N + bn + cl];
    }
    __syncthreads();
    #pragma unroll
    for (int k = 0; k < BKK; ++k) {
      float af[8], bf[8];
      *(float4*)&af[0] = *(const float4*)&As[k][ty * 8];
      *(float4*)&af[4] = *(const float4*)&As[k][ty * 8 + 4];
      *(float4*)&bf[0] = *(const float4*)&Bs[k][tx * 8];
      *(float4*)&bf[4] = *(const float4*)&Bs[k][tx * 8 + 4];
      #pragma unroll
      for (int i = 0; i < 8; ++i)
        #pragma unroll
        for (int j = 0; j < 8; ++j) acc[i][j] += af[i] * bf[j];
    }
    __syncthreads();
  }
  #pragma unroll
  for (int i = 0; i < 8; ++i) {
    size_t off = (size_t)(bm + ty * 8 + i) * N + bn + tx * 8;
    *(float4*)&C[off]     = make_float4(acc[i][0], acc[i][1], acc[i][2], acc[i][3]);
    *(float4*)&C[off + 4] = make_float4(acc[i][4], acc[i][5], acc[i][6], acc[i][7]);
  }
}

// ---------------------------------------------------------- causal conv K=4 + silu
__global__ __launch_bounds__(256) void conv_silu_k(const float* __restrict__ x,
    const float* __restrict__ w, float* __restrict__ y) {
  int idx = blockIdx.x * 256 + threadIdx.x;
  int ch = idx & (HID - 1);
  int n = idx >> 10;
  int l = n & (SEQ - 1);
  float4 wv = *(const float4*)&w[ch * 4];
  float s = wv.w * x[idx];
  if (l >= 1) s += wv.z * x[idx - HID];
  if (l >= 2) s += wv.y * x[idx - 2 * HID];
  if (l >= 3) s += wv.x * x[idx - 3 * HID];
  y[idx] = s / (1.f + expf(-s));   // silu
}

// ---------------------------------------------------------------- beta = sigmoid(hs@Wb)
__global__ __launch_bounds__(256) void beta_k(const float* __restrict__ hs,
    const float* __restrict__ Wb, float* __restrict__ beta) {
  int wv = threadIdx.x >> 6, lane = threadIdx.x & 63;
  int n = blockIdx.x * 4 + wv;
  const float* row = hs + (size_t)n * HID;
  float a0 = 0, a1 = 0, a2 = 0, a3 = 0;
  for (int k = lane; k < HID; k += 64) {
    float h = row[k];
    float4 wb = *(const float4*)&Wb[k * 4];
    a0 += h * wb.x; a1 += h * wb.y; a2 += h * wb.z; a3 += h * wb.w;
  }
  #pragma unroll
  for (int off = 32; off; off >>= 1) {
    a0 += __shfl_down(a0, off); a1 += __shfl_down(a1, off);
    a2 += __shfl_down(a2, off); a3 += __shfl_down(a3, off);
  }
  if (lane == 0) {
    float4 r = make_float4(1.f / (1.f + expf(-a0)), 1.f / (1.f + expf(-a1)),
                           1.f / (1.f + expf(-a2)), 1.f / (1.f + expf(-a3)));
    *(float4*)&beta[n * 4] = r;
  }
}

// --------------------------------------------- phase A (no spills)
__global__ __launch_bounds__(256) void phaseA_k(
    float* __restrict__ qg, float* __restrict__ kg, const float* __restrict__ vg,
    const float* __restrict__ betag, float* __restrict__ ug, float* __restrict__ wg,
    float* __restrict__ alg) {
  __shared__ __align__(16) float kn[32][260];
  __shared__ __align__(16) float qn[32][260];
  __shared__ __align__(16) float att[32][36];
  __shared__ float bet[32];
  int blk = blockIdx.x;
  int c = blk & (NCHUNK - 1);
  int bh = blk >> 7;
  int h = bh & 3, b = bh >> 2;
  int n0 = b * SEQ + c * 32;
  size_t rowbase = (size_t)n0 * HID + h * DK;
  int tid = threadIdx.x;
  int wv = tid >> 6, L = tid & 63;

  if (tid < 32) bet[tid] = betag[(n0 + tid) * NH + h];

  {  // stage + l2norm k
    float4 ka[8];
    #pragma unroll
    for (int j = 0; j < 8; ++j)
      ka[j] = *(const float4*)&kg[rowbase + (size_t)(wv + 4 * j) * HID + 4 * L];
    #pragma unroll
    for (int j = 0; j < 8; ++j) {
      float ss = ka[j].x * ka[j].x + ka[j].y * ka[j].y + ka[j].z * ka[j].z + ka[j].w * ka[j].w;
      #pragma unroll
      for (int m = 1; m < 64; m <<= 1) ss += __shfl_xor(ss, m);
      float sc = 1.f / sqrtf(ss + 1e-6f);
      int row = wv + 4 * j;
      float4 r = make_float4(ka[j].x * sc, ka[j].y * sc, ka[j].z * sc, ka[j].w * sc);
      *(float4*)&kn[row][4 * L] = r;
      *(float4*)&kg[rowbase + (size_t)row * HID + 4 * L] = r;
    }
  }
  {  // stage + l2norm q
    float4 qa[8];
    #pragma unroll
    for (int j = 0; j < 8; ++j)
      qa[j] = *(const float4*)&qg[rowbase + (size_t)(wv + 4 * j) * HID + 4 * L];
    #pragma unroll
    for (int j = 0; j < 8; ++j) {
      float ss = qa[j].x * qa[j].x + qa[j].y * qa[j].y + qa[j].z * qa[j].z + qa[j].w * qa[j].w;
      #pragma unroll
      for (int m = 1; m < 64; m <<= 1) ss += __shfl_xor(ss, m);
      float sc = 1.f / sqrtf(ss + 1e-6f);
      int row = wv + 4 * j;
      float4 r = make_float4(qa[j].x * sc, qa[j].y * sc, qa[j].z * sc, qa[j].w * sc);
      *(float4*)&qn[row][4 * L] = r;
      *(float4*)&qg[rowbase + (size_t)row * HID + 4 * L] = r;
    }
  }
  __syncthreads();

  {  // A = -(k*beta) @ kn^T strict-lower, 2x2 tile
    int i0 = (tid >> 4) << 1, j0 = (tid & 15) << 1;
    float a00 = 0, a01 = 0, a10 = 0, a11 = 0;
    #pragma unroll 4
    for (int e = 0; e < 256; e += 4) {
      float4 x0 = *(const float4*)&kn[i0][e];
      float4 x1 = *(const float4*)&kn[i0 + 1][e];
      float4 y0 = *(const float4*)&kn[j0][e];
      float4 y1 = *(const float4*)&kn[j0 + 1][e];
      a00 += x0.x * y0.x + x0.y * y0.y + x0.z * y0.z + x0.w * y0.w;
      a01 += x0.x * y1.x + x0.y * y1.y + x0.z * y1.z + x0.w * y1.w;
      a10 += x1.x * y0.x + x1.y * y0.y + x1.z * y0.z + x1.w * y0.w;
      a11 += x1.x * y1.x + x1.y * y1.y + x1.z * y1.z + x1.w * y1.w;
    }
    float bi0 = bet[i0], bi1 = bet[i0 + 1];
    att[i0][j0]         = (j0 < i0)         ? -bi0 * a00 : 0.f;
    att[i0][j0 + 1]     = (j0 + 1 < i0)     ? -bi0 * a01 : 0.f;
    att[i0 + 1][j0]     = (j0 < i0 + 1)     ? -bi1 * a10 : 0.f;
    att[i0 + 1][j0 + 1] = (j0 + 1 < i0 + 1) ? -bi1 * a11 : 0.f;
  }
  {  // attn_loc = (qn @ kn^T) * incl_low
    float* alp = alg + (size_t)(bh * NCHUNK + c) * 1024;
    int i0 = (tid >> 4) << 1, j0 = (tid & 15) << 1;
    float a00 = 0, a01 = 0, a10 = 0, a11 = 0;
    #pragma unroll 4
    for (int e = 0; e < 256; e += 4) {
      float4 x0 = *(const float4*)&qn[i0][e];
      float4 x1 = *(const float4*)&qn[i0 + 1][e];
      float4 y0 = *(const float4*)&kn[j0][e];
      float4 y1 = *(const float4*)&kn[j0 + 1][e];
      a00 += x0.x * y0.x + x0.y * y0.y + x0.z * y0.z + x0.w * y0.w;
      a01 += x0.x * y1.x + x0.y * y1.y + x0.z * y1.z + x0.w * y1.w;
      a10 += x1.x * y0.x + x1.y * y0.y + x1.z * y0.z + x1.w * y0.w;
      a11 += x1.x * y1.x + x1.y * y1.y + x1.z * y1.z + x1.w * y1.w;
    }
    alp[i0 * 32 + j0]           = (j0 <= i0)         ? a00 : 0.f;
    alp[i0 * 32 + j0 + 1]       = (j0 + 1 <= i0)     ? a01 : 0.f;
    alp[(i0 + 1) * 32 + j0]     = (j0 <= i0 + 1)     ? a10 : 0.f;
    alp[(i0 + 1) * 32 + j0 + 1] = (j0 + 1 <= i0 + 1) ? a11 : 0.f;
  }

  // prefetch v column into regs
  float vreg[32];
  {
    int d = tid;
    #pragma unroll
    for (int j = 0; j < 32; ++j)
      vreg[j] = vg[rowbase + (size_t)j * HID + d];
  }
  __syncthreads();

  // forward substitution in LDS (rolled, no register arrays)
  if (tid < 32) {
    int j = tid;
    for (int i = 1; i < 32; ++i) {
      float upd = 0.f;
      for (int k = j + 1; k < i; ++k)
        upd += att[i][k] * att[k][j];
      if (j < i) att[i][j] += upd;
    }
  }
  __syncthreads();

  {  // u = T@(v*beta), w = T@(k*beta); T = att + I
    int d = tid;
    #pragma unroll
    for (int j = 0; j < 32; ++j) vreg[j] *= bet[j];
    for (int i = 0; i < 32; ++i) {
      float s = vreg[i];
      #pragma unroll
      for (int j4 = 0; j4 < 32; j4 += 4) {
        float4 av = *(const float4*)&att[i][j4];
        s += av.x * vreg[j4] + av.y * vreg[j4 + 1] + av.z * vreg[j4 + 2] + av.w * vreg[j4 + 3];
      }
      ug[rowbase + (size_t)i * HID + d] = s;
    }
    float wreg[32];
    #pragma unroll
    for (int j = 0; j < 32; ++j) wreg[j] = kn[j][d] * bet[j];
    for (int i = 0; i < 32; ++i) {
      float s = wreg[i];
      #pragma unroll
      for (int j4 = 0; j4 < 32; j4 += 4) {
        float4 av = *(const float4*)&att[i][j4];
        s += av.x * wreg[j4] + av.y * wreg[j4 + 1] + av.z * wreg[j4 + 2] + av.w * wreg[j4 + 3];
      }
      wg[rowbase + (size_t)i * HID + d] = s;
    }
  }
}

// --------------------------------------------- phase B: sequential chunk scan
__device__ __forceinline__ void stage_rows_lds(const float* gbase, float* lds0,
                                               int wv, int L) {
  #pragma unroll
  for (int j = 0; j < 8; ++j) {
    int row = wv * 8 + j;
    const float* src = gbase + (size_t)row * HID + L * 4;
    float* dst = lds0 + row * 260;
    __builtin_amdgcn_global_load_lds(
        (const __attribute__((address_space(1))) unsigned int*)src,
        (__attribute__((address_space(3))) unsigned int*)dst, 16, 0, 0);
  }
}

__global__ __launch_bounds__(256) void scan_k(
    const float* __restrict__ qn, const float* __restrict__ kn,
    const float* __restrict__ ug, const float* __restrict__ wg,
    const float* __restrict__ alg, float* __restrict__ og) {
  __shared__ __align__(16) float S[256][8];
  __shared__ __align__(16) float stgw[32][260];
  __shared__ __align__(16) float stgq[32][260];
  __shared__ __align__(16) float stgk[32][260];
  __shared__ __align__(16) float albuf[32][33];
  __shared__ __align__(16) float uloc[32][12];
  __shared__ float red[8 * 296];

  int blk = blockIdx.x;
  int bh = blk & 7, dvg = blk >> 3;
  int h = bh & 3, b = bh >> 2;
  int d0 = dvg * 8;
  int tid = threadIdx.x;
  int wv = tid >> 6, L = tid & 63;
  int rP = tid >> 3, ks = tid & 7;
  int r2 = rP, dv2 = ks;

  #pragma unroll
  for (int i = 0; i < 8; ++i) ((float*)S)[tid + (i << 8)] = 0.f;

  size_t bhbase = (size_t)b * SEQ * HID + h * DK;
  const float* alp0 = alg + (size_t)bh * NCHUNK * 1024;

  stage_rows_lds(wg + bhbase, &stgw[0][0], wv, L);
  stage_rows_lds(qn + bhbase, &stgq[0][0], wv, L);
  stage_rows_lds(kn + bhbase, &stgk[0][0], wv, L);
  float alr0 = alp0[tid], alr1 = alp0[tid + 256], alr2 = alp0[tid + 512], alr3 = alp0[tid + 768];
  float u_cur = ug[bhbase + (size_t)r2 * HID + d0 + dv2];

  for (int c = 0; c < NCHUNK; ++c) {
    size_t rowbase = bhbase + (size_t)c * 32 * HID;
    __syncthreads();
    {
      albuf[tid >> 5][tid & 31] = alr0;
      albuf[(tid + 256) >> 5][tid & 31] = alr1;
      albuf[(tid + 512) >> 5][tid & 31] = alr2;
      albuf[(tid + 768) >> 5][tid & 31] = alr3;
    }
    float a0=0,a1=0,a2=0,a3=0,a4=0,a5=0,a6=0,a7=0;
    #pragma unroll
    for (int t = 0; t < 32; ++t) {
      int kk = (t << 3) + ks;
      float wvv = stgw[rP][kk];
      float4 s0 = *(const float4*)&S[kk][0];
      float4 s1 = *(const float4*)&S[kk][4];
      a0 += wvv*s0.x; a1 += wvv*s0.y; a2 += wvv*s0.z; a3 += wvv*s0.w;
      a4 += wvv*s1.x; a5 += wvv*s1.y; a6 += wvv*s1.z; a7 += wvv*s1.w;
    }
    {
      int base = rP * 9 + ks;
      red[0*296+base]=a0; red[1*296+base]=a1; red[2*296+base]=a2; red[3*296+base]=a3;
      red[4*296+base]=a4; red[5*296+base]=a5; red[6*296+base]=a6; red[7*296+base]=a7;
    }
    __syncthreads();
    {
      float s = 0.f;
      int base = dv2 * 296 + r2 * 9;
      #pragma unroll
      for (int k2 = 0; k2 < 8; ++k2) s += red[base + k2];
      uloc[r2][dv2] = u_cur - s;
    }
    __syncthreads();
    a0=0;a1=0;a2=0;a3=0;a4=0;a5=0;a6=0;a7=0;
    #pragma unroll
    for (int t = 0; t < 32; ++t) {
      int kk = (t << 3) + ks;
      float qvv = stgq[rP][kk];
      float4 s0 = *(const float4*)&S[kk][0];
      float4 s1 = *(const float4*)&S[kk][4];
      a0 += qvv*s0.x; a1 += qvv*s0.y; a2 += qvv*s0.z; a3 += qvv*s0.w;
      a4 += qvv*s1.x; a5 += qvv*s1.y; a6 += qvv*s1.z; a7 += qvv*s1.w;
    }
    {
      int base = rP * 9 + ks;
      red[0*296+base]=a0; red[1*296+base]=a1; red[2*296+base]=a2; red[3*296+base]=a3;
      red[4*296+base]=a4; red[5*296+base]=a5; red[6*296+base]=a6; red[7*296+base]=a7;
    }
    float d0r=0,d1r=0,d2r=0,d3r=0,d4r=0,d5r=0,d6r=0,d7r=0;
    #pragma unroll
    for (int rr = 0; rr < 32; ++rr) {
      float kv = stgk[rr][tid];
      float4 u0 = *(const float4*)&uloc[rr][0];
      float4 u1 = *(const float4*)&uloc[rr][4];
      d0r += kv*u0.x; d1r += kv*u0.y; d2r += kv*u0.z; d3r += kv*u0.w;
      d4r += kv*u1.x; d5r += kv*u1.y; d6r += kv*u1.z; d7r += kv*u1.w;
    }
    __syncthreads();
    if (c + 1 < NCHUNK) {
      size_t rbn = rowbase + (size_t)32 * HID;
      stage_rows_lds(wg + rbn, &stgw[0][0], wv, L);
      stage_rows_lds(qn + rbn, &stgq[0][0], wv, L);
      stage_rows_lds(kn + rbn, &stgk[0][0], wv, L);
      const float* alp = alp0 + (size_t)(c + 1) * 1024;
      alr0 = alp[tid]; alr1 = alp[tid + 256]; alr2 = alp[tid + 512]; alr3 = alp[tid + 768];
      u_cur = ug[rbn + (size_t)r2 * HID + d0 + dv2];
    }
    {
      float s = 0.f;
      int base = dv2 * 296 + r2 * 9;
      #pragma unroll
      for (int k2 = 0; k2 < 8; ++k2) s += red[base + k2];
      #pragma unroll
      for (int j2 = 0; j2 < 32; ++j2) s += albuf[r2][j2] * uloc[j2][dv2];
      og[rowbase + (size_t)r2 * HID + d0 + dv2] = s;
    }
    {
      float4 c0 = *(const float4*)&S[tid][0];
      float4 c1 = *(const float4*)&S[tid][4];
      c0.x += d0r; c0.y += d1r; c0.z += d2r; c0.w += d3r;
      c1.x += d4r; c1.y += d5r; c1.z += d6r; c1.w += d7r;
      *(float4*)&S[tid][0] = c0;
      *(float4*)&S[tid][4] = c1;
    }
  }
}

// -------------------------------------- fused depthwise FIR (K=64 long + K=5 short)
#define VS 196
__global__ __launch_bounds__(256) void fir_fused_k(const float* __restrict__ v,
    const float* __restrict__ wl, const float* __restrict__ wsrt,
    float* __restrict__ yl, float* __restrict__ ys) {
  __shared__ __align__(16) float vt[64 * VS];
  __shared__ __align__(16) float wlds[64 * 68];
  __shared__ float wslds[64 * 9];
  int blk = blockIdx.x;
  int ch0 = (blk & 15) << 6;
  int tok0 = (blk >> 4) << 7;
  int tid = threadIdx.x;
  {
    const float4* src = (const float4*)(wl + (size_t)ch0 * 64);
    #pragma unroll
    for (int i = 0; i < 4; ++i) {
      int f = tid + (i << 8);
      int c = f >> 4, g = f & 15;
      float4 x = src[f];
      *(float4*)&wlds[c * 68 + (g << 2)] = x;
    }
  }
  if (tid < 64) {
    #pragma unroll
    for (int j = 0; j < 5; ++j)
      wslds[tid * 9 + j] = wsrt[(size_t)(ch0 + tid) * 5 + j];
  }
  {
    int chg = tid & 15, rt = tid >> 4;
    int lb = tok0 & (SEQ - 1);
    #pragma unroll
    for (int m = 0; m < 12; ++m) {
      int rr = rt + (m << 4);
      if (rr < 191) {
        float4 x = make_float4(0.f, 0.f, 0.f, 0.f);
        if (lb + rr - 63 >= 0)
          x = *(const float4*)&v[(size_t)(tok0 - 63 + rr) * HID + ch0 + (chg << 2)];
        int cb = chg << 2;
        vt[(cb + 0) * VS + rr] = x.x;
        vt[(cb + 1) * VS + rr] = x.y;
        vt[(cb + 2) * VS + rr] = x.z;
        vt[(cb + 3) * VS + rr] = x.w;
      }
    }
  }
  __syncthreads();
  int ch = tid & 63, pt = tid >> 6;
  int p0 = pt << 5;
  const float* vrow = &vt[ch * VS + p0];
  float acc[32];
  #pragma unroll
  for (int p = 0; p < 32; ++p) acc[p] = 0.f;
  for (int g = 0; g < 16; ++g) {
    float win[36];
    #pragma unroll
    for (int j = 0; j < 9; ++j) {
      float4 x = *(const float4*)&vrow[(g << 2) + (j << 2)];
      win[4 * j] = x.x; win[4 * j + 1] = x.y; win[4 * j + 2] = x.z; win[4 * j + 3] = x.w;
    }
    float4 wq = *(const float4*)&wlds[ch * 68 + (g << 2)];
    #pragma unroll
    for (int p = 0; p < 32; ++p)
      acc[p] += wq.x * win[p] + wq.y * win[p + 1] + wq.z * win[p + 2] + wq.w * win[p + 3];
  }
  #pragma unroll
  for (int p = 0; p < 32; ++p)
    yl[(size_t)(tok0 + p0 + p) * HID + ch0 + ch] = acc[p];
  float ws5[5];
  #pragma unroll
  for (int j = 0; j < 5; ++j) ws5[j] = wslds[ch * 9 + j];
  float swin[40];
  #pragma unroll
  for (int j = 0; j < 10; ++j) {
    float4 x = *(const float4*)&vrow[56 + (j << 2)];
    swin[4 * j] = x.x; swin[4 * j + 1] = x.y; swin[4 * j + 2] = x.z; swin[4 * j + 3] = x.w;
  }
  #pragma unroll
  for (int p = 0; p < 32; ++p) {
    float s = ws5[0] * swin[p + 3] + ws5[1] * swin[p + 4] + ws5[2] * swin[p + 5]
            + ws5[3] * swin[p + 6] + ws5[4] * swin[p + 7];
    ys[(size_t)(tok0 + p0 + p) * HID + ch0 + ch] = s;
  }
}

// ---------------------------------------------------------------- stats
__global__ __launch_bounds__(256) void stats_k(const float* __restrict__ ls,
    const float* __restrict__ ll, const float* __restrict__ dd,
    const float* __restrict__ vv, float* __restrict__ st) {
  int n = blockIdx.x;
  int h = threadIdx.x >> 6, lane = threadIdx.x & 63;
  size_t base = (size_t)n * HID + h * DV;
  const float* ptr[4] = {ls, ll, dd, vv};
  #pragma unroll
  for (int t = 0; t < 4; ++t) {
    const float* p = ptr[t] + base;
    float s1 = 0, s2 = 0, sa = 0;
    #pragma unroll
    for (int e = 0; e < 4; ++e) {
      float x = p[lane + e * 64];
      s1 += x; s2 += x * x; sa += fabsf(x);
    }
    #pragma unroll
    for (int off = 32; off; off >>= 1) {
      s1 += __shfl_down(s1, off); s2 += __shfl_down(s2, off); sa += __shfl_down(sa, off);
    }
    if (lane == 0) {
      float mean = s1 * (1.f / 256.f);
      float var = s2 * (1.f / 256.f) - mean * mean;
      float4 r = make_float4(mean, var, sa * (1.f / 256.f), sqrtf(s2));
      *(float4*)&st[(size_t)(n * NH + h) * 16 + t * 4] = r;
    }
  }
}

// --------------------------------------- gate MLP tail + softmax + fuse + RMSNorm
__global__ __launch_bounds__(256) void gate_fuse_k(
    const float* __restrict__ base, const float* __restrict__ st,
    const float* __restrict__ w1b, const float* __restrict__ b1,
    const float* __restrict__ w2, const float* __restrict__ b2,
    const float* __restrict__ ltemp,
    const float* __restrict__ ls, const float* __restrict__ ll,
    const float* __restrict__ dd, const float* __restrict__ vv,
    const float* __restrict__ onw, float* __restrict__ fused) {
  int n = blockIdx.x, tid = threadIdx.x;
  __shared__ float sst[4][16];
  __shared__ float wred[4][16];
  __shared__ float probs[4][4];
  __shared__ float o2red[4][4];
  __shared__ float rmss[4];
  if (tid < 64) sst[tid >> 4][tid & 15] = st[(size_t)n * 64 + tid];
  __syncthreads();
  float acc[4][4];
  #pragma unroll
  for (int a = 0; a < 4; ++a)
    #pragma unroll
    for (int cc = 0; cc < 4; ++cc) acc[a][cc] = 0.f;
  #pragma unroll
  for (int jj = 0; jj < 4; ++jj) {
    int j = tid + (jj << 8);
    float xb = base[(size_t)n * HID + j] + b1[j];
    float wr[16];
    #pragma unroll
    for (int s = 0; s < 16; ++s) wr[s] = w1b[s * 1024 + j];
    float4 w2j = *(const float4*)&w2[j * 4];
    #pragma unroll
    for (int hh = 0; hh < 4; ++hh) {
      float x = xb;
      #pragma unroll
      for (int s = 0; s < 16; ++s) x += sst[hh][s] * wr[s];
      float g = 0.5f * x * (1.f + erff(x * 0.70710678118654752f));
      acc[hh][0] += g * w2j.x; acc[hh][1] += g * w2j.y;
      acc[hh][2] += g * w2j.z; acc[hh][3] += g * w2j.w;
    }
  }
  #pragma unroll
  for (int hh = 0; hh < 4; ++hh)
    #pragma unroll
    for (int cc = 0; cc < 4; ++cc) {
      float v = acc[hh][cc];
      #pragma unroll
      for (int off = 32; off; off >>= 1) v += __shfl_down(v, off);
      if ((tid & 63) == 0) wred[tid >> 6][hh * 4 + cc] = v;
    }
  __syncthreads();
  if (tid < 4) {
    int hh = tid;
    float t = expf(ltemp[hh]);
    float lg[4], mx = -1e30f;
    #pragma unroll
    for (int cc = 0; cc < 4; ++cc) {
      float sv = wred[0][hh * 4 + cc] + wred[1][hh * 4 + cc] + wred[2][hh * 4 + cc]
               + wred[3][hh * 4 + cc] + b2[cc];
      lg[cc] = sv / t;
      mx = fmaxf(mx, lg[cc]);
    }
    float se = 0.f;
    #pragma unroll
    for (int cc = 0; cc < 4; ++cc) { lg[cc] = expf(lg[cc] - mx); se += lg[cc]; }
    float inv = 1.f / se;
    #pragma unroll
    for (int cc = 0; cc < 4; ++cc) probs[hh][cc] = 0.05f + 0.8f * lg[cc] * inv;
  }
  __syncthreads();
  int d = tid;
  float ov[4];
  #pragma unroll
  for (int hh = 0; hh < 4; ++hh) {
    size_t ix = (size_t)n * HID + hh * DV + d;
    float o = probs[hh][0] * ls[ix] + probs[hh][1] * ll[ix]
            + probs[hh][2] * dd[ix] + probs[hh][3] * vv[ix];
    ov[hh] = o;
    float v2 = o * o;
    #pragma unroll
    for (int off = 32; off; off >>= 1) v2 += __shfl_down(v2, off);
    if ((tid & 63) == 0) o2red[tid >> 6][hh] = v2;
  }
  __syncthreads();
  if (tid < 4) {
    float s = o2red[0][tid] + o2red[1][tid] + o2red[2][tid] + o2red[3][tid];
    rmss[tid] = 1.f / sqrtf(s * (1.f / 256.f) + 1e-5f);
  }
  __syncthreads();
  float wn = onw[d];
  #pragma unroll
  for (int hh = 0; hh < 4; ++hh)
    fused[(size_t)n * HID + hh * DV + d] = ov[hh] * rmss[hh] * wn;
}

// ---------------------------------------------------------------- launch
extern "C" void kernel_launch(void* const* d_in, const int* in_sizes, int n_in,
                              void* d_out, int out_size, void* d_ws, size_t ws_size,
                              hipStream_t stream) {
  (void)in_sizes; (void)n_in; (void)out_size; (void)ws_size;
  const float* hs  = (const float*)d_in[0];
  const float* Wq  = (const float*)d_in[1];
  const float* Wk  = (const float*)d_in[2];
  const float* Wv  = (const float*)d_in[3];
  const float* Wb  = (const float*)d_in[4];
  const float* cqw = (const float*)d_in[5];
  const float* ckw = (const float*)d_in[6];
  const float* cvw = (const float*)d_in[7];
  const float* fsw = (const float*)d_in[8];
  const float* flw = (const float*)d_in[9];
  const float* w1  = (const float*)d_in[10];
  const float* b1  = (const float*)d_in[11];
  const float* w2  = (const float*)d_in[12];
  const float* b2  = (const float*)d_in[13];
  const float* lt  = (const float*)d_in[14];
  const float* onw = (const float*)d_in[15];
  const float* Wo  = (const float*)d_in[16];
  float* out = (float*)d_out;
  float* ws = (float*)d_ws;
  const size_t BIG = (size_t)NTOK * HID;
  float* lin = ws;
  float* qb  = ws + BIG;
  float* kb  = ws + 2 * BIG;
  float* vb  = ws + 3 * BIG;
  float* ub  = ws + 4 * BIG;
  float* wb  = ws + 5 * BIG;
  float* db  = ws + 6 * BIG;
  float* betab  = ws + 7 * BIG;
  float* statsb = betab + (size_t)NTOK * NH;
  float* alocb  = statsb + (size_t)NTOK * NH * 16;

  dim3 gb(HID / 128, NTOK / 128);      // bf16 MFMA gemms
  dim3 gg(HID / BN, NTOK / BM);        // fp32 gemm (Wo)
  gemm_bf16<<<gb, 256, 0, stream>>>(hs, Wq, lin, NTOK, HID, HID);
  conv_silu_k<<<NTOK * HID / 256, 256, 0, stream>>>(lin, cqw, qb);
  gemm_bf16<<<gb, 256, 0, stream>>>(hs, Wk, lin, NTOK, HID, HID);
  conv_silu_k<<<NTOK * HID / 256, 256, 0, stream>>>(lin, ckw, kb);
  gemm_bf16<<<gb, 256, 0, stream>>>(hs, Wv, lin, NTOK, HID, HID);
  conv_silu_k<<<NTOK * HID / 256, 256, 0, stream>>>(lin, cvw, vb);
  beta_k<<<NTOK / 4, 256, 0, stream>>>(hs, Wb, betab);
  phaseA_k<<<2 * NH * NCHUNK, 256, 0, stream>>>(qb, kb, vb, betab, ub, wb, alocb);
  scan_k<<<256, 256, 0, stream>>>(qb, kb, ub, wb, alocb, db);
  fir_fused_k<<<(NTOK / 128) * (HID / 64), 256, 0, stream>>>(vb, flw, fsw, kb, qb);
  stats_k<<<NTOK, 256, 0, stream>>>(qb, kb, db, vb, statsb);
  gemm_bf16<<<gb, 256, 0, stream>>>(hs, w1, wb, NTOK, HID, HID);
  gate_fuse_k<<<NTOK, 256, 0, stream>>>(wb, statsb, w1 + 1024 * 1024, b1, w2, b2, lt,
                                        qb, kb, db, vb, onw, ub);
  gemm_f32<<<gg, 256, 0, stream>>>(ub, Wo, out, NTOK, HID, HID);
}